// Round 2
// baseline (1023.617 us; speedup 1.0000x reference)
//
#include <hip/hip_runtime.h>
#include <hip/hip_cooperative_groups.h>

namespace cg = cooperative_groups;

#define RANK 16
#define EMBED_DIM 128
#define SCAN_TILE 1024  // 256 threads x 4 items per scan chunk

// ---------------------------------------------------------------------------
// Single persistent cooperative kernel. Phases separated by grid.sync():
//   P0: zero off[0..N], per-block dtype detection (odd words of int64 layout
//       are high halves of node ids -> all zero; int32 layout -> random ids,
//       essentially surely nonzero among 256 samples).
//   P1: histogram of dst into off[]          (1 int atomic / edge)
//   P2: exclusive scan of off[] (S1 per-1024-chunk, S2 block0 over <=256
//       chunk sums, S3 apply + mirror into cur[], off[N]=E)
//   P3: reorder src ids into per-dst CSR segments (1 atomic + 4B write / edge)
//   P4: fused gather+project: 16 lanes walk a node's segment accumulating the
//       rank-16 row (atomic-free, deterministic), then 256 threads emit the
//       32-node x 128-col tile as float4 stores through LDS-cached V.
// All loops are grid-stride; every block reaches every grid.sync().
// ---------------------------------------------------------------------------
__global__ __launch_bounds__(256) void fused_all(
        const float* __restrict__ U,
        const float* __restrict__ V,
        const int* __restrict__ eiw,     // edge_index as 32-bit words
        float* __restrict__ out,
        int* __restrict__ off,           // [N+1]
        int* __restrict__ cur,           // [N]
        int* __restrict__ bsums,         // [256]
        int* __restrict__ ssrc,          // [E]
        int N, int E, int nwords) {
    cg::grid_group grid = cg::this_grid();

    __shared__ float4 Vs4[RANK * EMBED_DIM / 4];  // 8 KB
    __shared__ float accs[32][RANK];              // 2 KB
    __shared__ float sinv[32];
    __shared__ int idat[256];                     // scan scratch
    __shared__ int iflag;

    const int t = threadIdx.x;
    const int bid = blockIdx.x;
    const int nb = gridDim.x;
    const int gstride = nb * 256;

    // ---- P0: dtype detect (per-block, deterministic) + zero off ----
    if (t == 0) iflag = 0;
    __syncthreads();
    {
        int w = 2 * t + 1;
        unsigned int v = (w < nwords) ? ((const unsigned int*)eiw)[w] : 0u;
        if (v) atomicOr(&iflag, 1);
    }
    for (int i = bid * 256 + t; i <= N; i += gstride) off[i] = 0;
    __syncthreads();
    const bool is32 = (iflag != 0);

    __threadfence();
    grid.sync();

    // ---- P1: histogram ----
    for (int e = bid * 256 + t; e < E; e += gstride) {
        int dst = is32 ? eiw[E + e] : eiw[2 * (E + e)];
        atomicAdd(&off[dst], 1);
    }
    __threadfence();
    grid.sync();

    // ---- P2.S1: per-chunk exclusive scan + chunk sums ----
    const int NB = (N + SCAN_TILE - 1) / SCAN_TILE;  // 196 (<=256 required)
    for (int b = bid; b < NB; b += nb) {
        int base = b * SCAN_TILE + t * 4;
        int c0 = 0, c1 = 0, c2 = 0, c3 = 0;
        if (base + 3 < N) {
            int4 v = *(const int4*)(off + base);
            c0 = v.x; c1 = v.y; c2 = v.z; c3 = v.w;
        } else {
            if (base + 0 < N) c0 = off[base + 0];
            if (base + 1 < N) c1 = off[base + 1];
            if (base + 2 < N) c2 = off[base + 2];
            if (base + 3 < N) c3 = off[base + 3];
        }
        int s = c0 + c1 + c2 + c3;
        idat[t] = s;
        __syncthreads();
        for (int d = 1; d < 256; d <<= 1) {
            int v = (t >= d) ? idat[t - d] : 0;
            __syncthreads();
            idat[t] += v;
            __syncthreads();
        }
        int excl = idat[t] - s;
        if (t == 255) bsums[b] = idat[255];
        if (base + 3 < N) {
            int4 o;
            o.x = excl;
            o.y = excl + c0;
            o.z = excl + c0 + c1;
            o.w = excl + c0 + c1 + c2;
            *(int4*)(off + base) = o;
        } else {
            if (base + 0 < N) off[base + 0] = excl;
            if (base + 1 < N) off[base + 1] = excl + c0;
            if (base + 2 < N) off[base + 2] = excl + c0 + c1;
            if (base + 3 < N) off[base + 3] = excl + c0 + c1 + c2;
        }
        __syncthreads();
    }
    __threadfence();
    grid.sync();

    // ---- P2.S2: block 0 scans the chunk sums ----
    if (bid == 0) {
        int s = (t < NB) ? bsums[t] : 0;
        idat[t] = s;
        __syncthreads();
        for (int d = 1; d < 256; d <<= 1) {
            int v = (t >= d) ? idat[t - d] : 0;
            __syncthreads();
            idat[t] += v;
            __syncthreads();
        }
        if (t < NB) bsums[t] = idat[t] - s;
    }
    __threadfence();
    grid.sync();

    // ---- P2.S3: apply chunk offsets, mirror into cur ----
    for (int i = bid * 256 + t; i < N; i += gstride) {
        int v = off[i] + bsums[i >> 10];
        off[i] = v;
        cur[i] = v;
    }
    if (bid == 0 && t == 0) off[N] = E;
    __threadfence();
    grid.sync();

    // ---- P3: reorder src ids into CSR segments ----
    for (int e = bid * 256 + t; e < E; e += gstride) {
        int src, dst;
        if (is32) {
            src = eiw[e];
            dst = eiw[E + e];
        } else {
            src = eiw[2 * e];
            dst = eiw[2 * (E + e)];
        }
        int pos = atomicAdd(&cur[dst], 1);
        ssrc[pos] = src;
    }
    __threadfence();
    grid.sync();

    // ---- P4: fused gather + project ----
    const float4* V4 = (const float4*)V;
    Vs4[t] = V4[t];
    Vs4[t + 256] = V4[t + 256];

    const int ntiles = (N + 31) / 32;
    const int g = t >> 4;   // node group 0..15 (phase A)
    const int j = t & 15;   // rank lane       (phase A)
    const int q = t & 31;   // float4 column   (phase B)
    const int w = t >> 5;   // node quad       (phase B)

    for (int tile = bid; tile < ntiles; tile += nb) {
        __syncthreads();  // prev tile's phase-B reads done; Vs4 visible
#pragma unroll
        for (int half = 0; half < 2; ++half) {
            int nd = half * 16 + g;
            int n = tile * 32 + nd;
            int o0 = 0, o1 = 0;
            if (n < N) { o0 = off[n]; o1 = off[n + 1]; }
            float acc = 0.f;
            for (int e = o0; e < o1; ++e) {
                int s = ssrc[e];                    // broadcast read
                acc += U[(size_t)s * RANK + j];     // 64B coalesced row
            }
            accs[nd][j] = acc;
            if (j == 0) sinv[nd] = 1.0f / fmaxf((float)(o1 - o0), 1.0f);
        }
        __syncthreads();
#pragma unroll
        for (int r = 0; r < 4; ++r) {
            int nd = 4 * w + r;
            float4 a4 = make_float4(0.f, 0.f, 0.f, 0.f);
#pragma unroll
            for (int k = 0; k < RANK; ++k) {
                float a = accs[nd][k];              // broadcast
                float4 v = Vs4[k * 32 + q];
                a4.x = fmaf(a, v.x, a4.x);
                a4.y = fmaf(a, v.y, a4.y);
                a4.z = fmaf(a, v.z, a4.z);
                a4.w = fmaf(a, v.w, a4.w);
            }
            float s = sinv[nd];
            int n = tile * 32 + nd;
            if (n < N)
                ((float4*)out)[(size_t)n * (EMBED_DIM / 4) + q] =
                    make_float4(a4.x * s, a4.y * s, a4.z * s, a4.w * s);
        }
    }
}

extern "C" void kernel_launch(void* const* d_in, const int* in_sizes, int n_in,
                              void* d_out, int out_size, void* d_ws, size_t ws_size,
                              hipStream_t stream) {
    const float* U = (const float*)d_in[0];
    const float* V = (const float*)d_in[1];
    const int* EI = (const int*)d_in[2];
    float* out = (float*)d_out;

    int N = in_sizes[0] / RANK;   // 200000
    int E = in_sizes[2] / 2;      // 640000
    int nwords = in_sizes[2];     // safe lower bound on 32-bit word count

    // workspace layout (all int32): off[N+1] | cur[N] | bsums[256] | ssrc[E]
    int* off   = (int*)d_ws;
    int* cur   = off + (N + 1);
    int* bsums = cur + N;
    int* ssrc  = bsums + 256;

    // Persistent-grid size: max co-resident blocks (cached; host-only queries).
    static int g_grid = 0;
    if (g_grid == 0) {
        int dev = 0;
        hipGetDevice(&dev);
        hipDeviceProp_t prop;
        hipGetDeviceProperties(&prop, dev);
        int maxb = 0;
        if (hipOccupancyMaxActiveBlocksPerMultiprocessor(&maxb, fused_all, 256, 0)
                != hipSuccess || maxb <= 0)
            maxb = 4;
        g_grid = prop.multiProcessorCount * maxb;
        if (g_grid <= 0) g_grid = 1024;
    }

    void* args[] = {(void*)&U, (void*)&V, (void*)&EI, (void*)&out,
                    (void*)&off, (void*)&cur, (void*)&bsums, (void*)&ssrc,
                    (void*)&N, (void*)&E, (void*)&nwords};
    hipLaunchCooperativeKernel((void*)fused_all, dim3(g_grid), dim3(256),
                               args, 0, stream);
}

// Round 3
// 199.586 us; speedup vs baseline: 5.1287x; 5.1287x over previous
//
#include <hip/hip_runtime.h>

#define RANK 16
#define EMBED_DIM 128
#define CAP 32   // max in-slot degree; E/N = 3.2 avg, P(deg>=32) ~ 1e-24

// ---------------------------------------------------------------------------
// K1: one pass over edges. Per-block dtype detect (odd 32-bit words of an
// int64 layout are high halves of node ids < 2^31 -> all zero; int32 layout
// -> random ids, surely nonzero among 256 samples). Then:
//   pos = atomicAdd(cnt[dst]); pos < CAP ? slots[dst*CAP+pos] = src
//                                        : append (src,dst) to overflow list.
// 1 int atomic + one 4B write per edge (vs 17 atomics/edge in the original).
// ---------------------------------------------------------------------------
__global__ __launch_bounds__(256) void fill_slots(
        const int* __restrict__ eiw,   // edge_index as 32-bit words
        int* __restrict__ cnt,         // [N], pre-zeroed
        int* __restrict__ ovfcnt,      // [1], pre-zeroed
        int* __restrict__ slots,       // [N*CAP]
        int* __restrict__ ovf,         // [2*E]
        int E, int nwords) {
    __shared__ int iflag;
    if (threadIdx.x == 0) iflag = 0;
    __syncthreads();
    {
        int w = 2 * threadIdx.x + 1;
        unsigned int v = (w < nwords) ? ((const unsigned int*)eiw)[w] : 0u;
        if (v) atomicOr(&iflag, 1);            // LDS atomic
    }
    __syncthreads();
    const bool is32 = (iflag != 0);

    int e = blockIdx.x * 256 + threadIdx.x;
    if (e >= E) return;
    int src, dst;
    if (is32) {                 // int32 layout
        src = eiw[e];
        dst = eiw[E + e];
    } else {                    // int64 layout (little-endian low words)
        src = eiw[2 * e];
        dst = eiw[2 * (E + e)];
    }
    int pos = atomicAdd(&cnt[dst], 1);
    if (pos < CAP) {
        slots[(size_t)dst * CAP + pos] = src;
    } else {                    // essentially never on sane inputs
        int o = atomicAdd(ovfcnt, 1);
        ovf[2 * o]     = src;
        ovf[2 * o + 1] = dst;
    }
}

// ---------------------------------------------------------------------------
// K2: fused atomic-free gather + projection. Block = 256 threads, 32 nodes.
// Stage slots tile (32x32 ints, contiguous 4KB) + counts into LDS.
// Phase A: group g (16 lanes, lane j = rank) sums U[src][j] over the node's
//          slot list -> accs[32][16] (sequential, deterministic).
// Phase B: thread (q = t&31, w = t>>5) emits 4 nodes x float4 columns of
//          (accs/deg) @ V with V LDS-cached.
// Overflow fallback (deg > CAP): scan the global overflow list. Correct for
// arbitrary inputs; never taken on random graphs.
// ---------------------------------------------------------------------------
__global__ __launch_bounds__(256) void gather_project(
        const float* __restrict__ U,
        const float* __restrict__ V,
        const int* __restrict__ cnt,
        const int* __restrict__ slots,
        const int* __restrict__ ovfcnt,
        const int* __restrict__ ovf,
        float* __restrict__ out, int N) {
    __shared__ float4 Vs4[RANK * EMBED_DIM / 4];  // 8 KB
    __shared__ float accs[32][RANK];              // 2 KB
    __shared__ float sinv[32];
    __shared__ int   scnt[32];
    __shared__ int   sslot[32][CAP + 1];          // +1 pad: groups hit
                                                  // different banks

    const int t = threadIdx.x;
    const float4* V4 = (const float4*)V;
    Vs4[t]       = V4[t];
    Vs4[t + 256] = V4[t + 256];

    const int n0 = blockIdx.x * 32;

    if (t < 32) {
        int n = n0 + t;
        int c = (n < N) ? cnt[n] : 0;
        scnt[t] = c;
        sinv[t] = 1.0f / fmaxf((float)c, 1.0f);
    }
    // stage slot tile: 32 nodes x 32 ints = 256 int4, contiguous 4 KB
    {
        const int4* g4 = (const int4*)(slots + (size_t)n0 * CAP);
        int nd = t >> 3;
        if (n0 + nd < N) {
            int4 v = g4[t];
            sslot[nd][(t & 7) * 4 + 0] = v.x;
            sslot[nd][(t & 7) * 4 + 1] = v.y;
            sslot[nd][(t & 7) * 4 + 2] = v.z;
            sslot[nd][(t & 7) * 4 + 3] = v.w;
        }
    }
    __syncthreads();

    const int g = t >> 4;   // node group 0..15
    const int j = t & 15;   // rank lane
#pragma unroll
    for (int half = 0; half < 2; ++half) {
        int nd = half * 16 + g;
        int n = n0 + nd;
        float acc = 0.f;
        if (n < N) {
            int deg = scnt[nd];
            int k = deg < CAP ? deg : CAP;
            for (int e = 0; e < k; ++e) {
                int s = sslot[nd][e];               // LDS broadcast
                acc += U[(size_t)s * RANK + j];     // 64B coalesced row
            }
            if (deg > CAP) {                        // correctness fallback
                int m = *ovfcnt;
                for (int i = 0; i < m; ++i)
                    if (ovf[2 * i + 1] == n)
                        acc += U[(size_t)ovf[2 * i] * RANK + j];
            }
        }
        accs[nd][j] = acc;
    }
    __syncthreads();

    const int q = t & 31;   // float4 column
    const int w = t >> 5;   // node quad
#pragma unroll
    for (int r = 0; r < 4; ++r) {
        int nd = 4 * w + r;
        float4 a4 = make_float4(0.f, 0.f, 0.f, 0.f);
#pragma unroll
        for (int k = 0; k < RANK; ++k) {
            float a = accs[nd][k];                  // broadcast / 2-way: free
            float4 v = Vs4[k * 32 + q];
            a4.x = fmaf(a, v.x, a4.x);
            a4.y = fmaf(a, v.y, a4.y);
            a4.z = fmaf(a, v.z, a4.z);
            a4.w = fmaf(a, v.w, a4.w);
        }
        float s = sinv[nd];
        int n = n0 + nd;
        if (n < N)
            ((float4*)out)[(size_t)n * (EMBED_DIM / 4) + q] =
                make_float4(a4.x * s, a4.y * s, a4.z * s, a4.w * s);
    }
}

extern "C" void kernel_launch(void* const* d_in, const int* in_sizes, int n_in,
                              void* d_out, int out_size, void* d_ws, size_t ws_size,
                              hipStream_t stream) {
    const float* U = (const float*)d_in[0];
    const float* V = (const float*)d_in[1];
    const int* EI = (const int*)d_in[2];
    float* out = (float*)d_out;

    const int N = in_sizes[0] / RANK;   // 200000
    const int E = in_sizes[2] / 2;      // 640000
    const int nwords = in_sizes[2];     // >= word count under both layouts

    // workspace (int32): cnt[N] | ovfcnt[1] | pad | slots[N*CAP] | ovf[2E]
    int* wsI = (int*)d_ws;
    int* cnt = wsI;
    int* ovfcnt = wsI + N;
    const int slots_off = (N + 1 + 15) & ~15;   // 16B-align slots for int4
    int* slots = wsI + slots_off;
    int* ovf = slots + (size_t)N * CAP;         // N*CAP % 16 == 0

    // zero cnt + ovfcnt only (0.8 MB)
    hipMemsetAsync(d_ws, 0, (size_t)(N + 1) * sizeof(int), stream);

    fill_slots<<<(E + 255) / 256, 256, 0, stream>>>(
        EI, cnt, ovfcnt, slots, ovf, E, nwords);

    gather_project<<<(N + 31) / 32, 256, 0, stream>>>(
        U, V, cnt, slots, ovfcnt, ovf, out, N);
}

// Round 5
// 187.671 us; speedup vs baseline: 5.4543x; 1.0635x over previous
//
#include <hip/hip_runtime.h>

#define RANK 16
#define EMBED_DIM 128
#define CAP 16   // slot capacity; Poisson(3.2) P(deg>16) ~ 1e-8/node.
                 // Overflow list keeps arbitrary inputs correct.

typedef float floatx4 __attribute__((ext_vector_type(4)));  // clang-native:
// __builtin_nontemporal_store accepts this (HIP float4 is a class, rejected).

// ---------------------------------------------------------------------------
// K1: one pass over edges, 4 edges/thread. Per-block dtype detect (odd 32-bit
// words of an int64 layout are high halves of node ids < 2^31 -> all zero;
// int32 layout -> random ids, surely nonzero among 256 samples). Then:
//   pos = atomicAdd(cnt[dst]); pos < CAP ? slots[dst*CAP+pos] = src
//                                        : append (src,dst) to overflow list.
// ---------------------------------------------------------------------------
__global__ __launch_bounds__(256) void fill_slots(
        const int* __restrict__ eiw,   // edge_index as 32-bit words
        int* __restrict__ cnt,         // [N], pre-zeroed
        int* __restrict__ ovfcnt,      // [1], pre-zeroed
        int* __restrict__ slots,       // [N*CAP]
        int* __restrict__ ovf,         // [2*E]
        int E, int nwords) {
    __shared__ int iflag;
    if (threadIdx.x == 0) iflag = 0;
    __syncthreads();
    {
        int w = 2 * threadIdx.x + 1;
        unsigned int v = (w < nwords) ? ((const unsigned int*)eiw)[w] : 0u;
        if (v) atomicOr(&iflag, 1);            // LDS atomic
    }
    __syncthreads();
    const bool is32 = (iflag != 0);

    const int base = (blockIdx.x * 256 + threadIdx.x) * 4;
    if (base >= E) return;

    int srcs[4], dsts[4];
    int ne;
    if ((E & 3) == 0 && base + 3 < E) {        // vector path (aligned)
        ne = 4;
        if (is32) {                            // int32 layout
            int4 s = *(const int4*)(eiw + base);
            int4 d = *(const int4*)(eiw + E + base);
            srcs[0] = s.x; srcs[1] = s.y; srcs[2] = s.z; srcs[3] = s.w;
            dsts[0] = d.x; dsts[1] = d.y; dsts[2] = d.z; dsts[3] = d.w;
        } else {                               // int64 layout: low words
            const int4* p = (const int4*)(eiw + 2 * base);
            const int4* q = (const int4*)(eiw + 2 * (E + base));
            int4 v0 = p[0], v1 = p[1], d0 = q[0], d1 = q[1];
            srcs[0] = v0.x; srcs[1] = v0.z; srcs[2] = v1.x; srcs[3] = v1.z;
            dsts[0] = d0.x; dsts[1] = d0.z; dsts[2] = d1.x; dsts[3] = d1.z;
        }
    } else {                                   // scalar tail / odd shapes
        ne = 0;
        for (int e = base; e < E && e < base + 4; ++e, ++ne) {
            srcs[ne] = is32 ? eiw[e] : eiw[2 * e];
            dsts[ne] = is32 ? eiw[E + e] : eiw[2 * (E + e)];
        }
    }

#pragma unroll
    for (int j = 0; j < 4; ++j) {
        if (j >= ne) break;
        int dst = dsts[j];
        int pos = atomicAdd(&cnt[dst], 1);
        if (pos < CAP) {
            slots[(size_t)dst * CAP + pos] = srcs[j];
        } else {                               // essentially never
            int o = atomicAdd(ovfcnt, 1);
            ovf[2 * o]     = srcs[j];
            ovf[2 * o + 1] = dst;
        }
    }
}

// ---------------------------------------------------------------------------
// K2: fused atomic-free gather + projection. Block = 256 threads, 32 nodes.
// Stage slot tile (32x16 ints = 2KB, linear ds_write_b128) + counts into LDS.
// Phase A: group g (16 lanes, lane j = rank) sums U[src][j] over the node's
//          slot list (sequential, deterministic). Overflow fallback scans the
//          tiny global overflow list (correct for arbitrary inputs).
// Phase B: thread (q = t&31, w = t>>5) emits 4 nodes x float4 columns of
//          (accs/deg) @ V with V LDS-cached; nontemporal stores keep the
//          102 MB output stream from evicting L2-resident U/slots.
// ---------------------------------------------------------------------------
__global__ __launch_bounds__(256) void gather_project(
        const float* __restrict__ U,
        const float* __restrict__ V,
        const int* __restrict__ cnt,
        const int* __restrict__ slots,
        const int* __restrict__ ovfcnt,
        const int* __restrict__ ovf,
        float* __restrict__ out, int N) {
    __shared__ float4 Vs4[RANK * EMBED_DIM / 4];  // 8 KB
    __shared__ float accs[32][RANK];              // 2 KB
    __shared__ float sinv[32];
    __shared__ int   scnt[32];
    __shared__ int4  sslot4[32 * CAP / 4];        // 2 KB, flat/linear

    const int t = threadIdx.x;
    const float4* V4 = (const float4*)V;
    Vs4[t]       = V4[t];
    Vs4[t + 256] = V4[t + 256];

    const int n0 = blockIdx.x * 32;

    if (t < 32) {
        int n = n0 + t;
        int c = (n < N) ? cnt[n] : 0;
        scnt[t] = c;
        sinv[t] = 1.0f / fmaxf((float)c, 1.0f);
    }
    if (t < 128) {                   // 32 nodes x 16 ints = 128 int4, linear
        const int4* g4 = (const int4*)(slots + (size_t)n0 * CAP);
        if (n0 + (t >> 2) < N) sslot4[t] = g4[t];
    }
    __syncthreads();

    const int* sslot = (const int*)sslot4;
    const int g = t >> 4;   // node group 0..15
    const int j = t & 15;   // rank lane
#pragma unroll
    for (int half = 0; half < 2; ++half) {
        int nd = half * 16 + g;
        int n = n0 + nd;
        float acc = 0.f;
        if (n < N) {
            int deg = scnt[nd];
            int k = deg < CAP ? deg : CAP;
            for (int e = 0; e < k; ++e) {
                int s = sslot[nd * CAP + e];        // LDS broadcast
                acc += U[(size_t)s * RANK + j];     // 64B coalesced row
            }
            if (deg > CAP) {                        // correctness fallback
                int m = *ovfcnt;
                for (int i = 0; i < m; ++i)
                    if (ovf[2 * i + 1] == n)
                        acc += U[(size_t)ovf[2 * i] * RANK + j];
            }
        }
        accs[nd][j] = acc;
    }
    __syncthreads();

    const int q = t & 31;   // float4 column
    const int w = t >> 5;   // node quad
#pragma unroll
    for (int r = 0; r < 4; ++r) {
        int nd = 4 * w + r;
        float4 a4 = make_float4(0.f, 0.f, 0.f, 0.f);
#pragma unroll
        for (int k = 0; k < RANK; ++k) {
            float a = accs[nd][k];                  // broadcast / 2-way: free
            float4 v = Vs4[k * 32 + q];
            a4.x = fmaf(a, v.x, a4.x);
            a4.y = fmaf(a, v.y, a4.y);
            a4.z = fmaf(a, v.z, a4.z);
            a4.w = fmaf(a, v.w, a4.w);
        }
        float s = sinv[nd];
        int n = n0 + nd;
        if (n < N) {
            floatx4 o;
            o.x = a4.x * s; o.y = a4.y * s; o.z = a4.z * s; o.w = a4.w * s;
            __builtin_nontemporal_store(
                o, (floatx4*)out + (size_t)n * (EMBED_DIM / 4) + q);
        }
    }
}

extern "C" void kernel_launch(void* const* d_in, const int* in_sizes, int n_in,
                              void* d_out, int out_size, void* d_ws, size_t ws_size,
                              hipStream_t stream) {
    const float* U = (const float*)d_in[0];
    const float* V = (const float*)d_in[1];
    const int* EI = (const int*)d_in[2];
    float* out = (float*)d_out;

    const int N = in_sizes[0] / RANK;   // 200000
    const int E = in_sizes[2] / 2;      // 640000
    const int nwords = in_sizes[2];     // >= word count under both layouts

    // workspace (int32): cnt[N] | ovfcnt[1] | pad | slots[N*CAP] | ovf[2E]
    int* wsI = (int*)d_ws;
    int* cnt = wsI;
    int* ovfcnt = wsI + N;
    const int slots_off = (N + 1 + 15) & ~15;   // 16B-align slots for int4
    int* slots = wsI + slots_off;
    int* ovf = slots + (size_t)N * CAP;         // N*CAP % 4 == 0

    // zero cnt + ovfcnt only (0.8 MB)
    hipMemsetAsync(d_ws, 0, (size_t)(N + 1) * sizeof(int), stream);

    fill_slots<<<(E + 1023) / 1024, 256, 0, stream>>>(
        EI, cnt, ovfcnt, slots, ovf, E, nwords);

    gather_project<<<(N + 31) / 32, 256, 0, stream>>>(
        U, V, cnt, slots, ovfcnt, ovf, out, N);
}

// Round 6
// 180.385 us; speedup vs baseline: 5.6746x; 1.0404x over previous
//
#include <hip/hip_runtime.h>

#define RANK 16
#define EMBED_DIM 128
#define CAP 16   // slot capacity; Poisson(3.2) P(deg>16) ~ 1e-8/node.
                 // Overflow list keeps arbitrary inputs correct.

typedef float floatx4 __attribute__((ext_vector_type(4)));  // clang-native:
// __builtin_nontemporal_store accepts this (HIP float4 is a class, rejected).

// ---------------------------------------------------------------------------
// K1: one pass over edges, 2 edges/thread (16B vector loads, 1250 blocks ->
// ~5 blocks/CU: enough TLP to hide atomic+scattered-store latency; R5's
// 4/thread starved the CUs at 2.4 blocks/CU). Per-block dtype detect (odd
// 32-bit words of int64 layout are high halves of node ids < 2^31 -> all
// zero; int32 layout -> random ids, surely nonzero among 256 samples). Then:
//   pos = atomicAdd(cnt[dst]); pos < CAP ? slots[dst*CAP+pos] = src
//                                        : append (src,dst) to overflow list.
// ---------------------------------------------------------------------------
__global__ __launch_bounds__(256) void fill_slots(
        const int* __restrict__ eiw,   // edge_index as 32-bit words
        int* __restrict__ cnt,         // [N], pre-zeroed
        int* __restrict__ ovfcnt,      // [1], pre-zeroed
        int* __restrict__ slots,       // [N*CAP]
        int* __restrict__ ovf,         // [2*E]
        int E, int nwords) {
    __shared__ int iflag;
    if (threadIdx.x == 0) iflag = 0;
    __syncthreads();
    {
        int w = 2 * threadIdx.x + 1;
        unsigned int v = (w < nwords) ? ((const unsigned int*)eiw)[w] : 0u;
        if (v) atomicOr(&iflag, 1);            // LDS atomic
    }
    __syncthreads();
    const bool is32 = (iflag != 0);

    const int base = (blockIdx.x * 256 + threadIdx.x) * 2;
    if (base >= E) return;

    int srcs[2], dsts[2];
    int ne;
    if ((E & 1) == 0 && base + 1 < E) {        // vector path (aligned: E even)
        ne = 2;
        if (is32) {                            // int32 layout: int2 loads
            int2 s = *(const int2*)(eiw + base);
            int2 d = *(const int2*)(eiw + E + base);
            srcs[0] = s.x; srcs[1] = s.y;
            dsts[0] = d.x; dsts[1] = d.y;
        } else {                               // int64 layout: int4, low words
            int4 sv = *(const int4*)(eiw + 2 * base);        // s0.lo s0.hi s1.lo s1.hi
            int4 dv = *(const int4*)(eiw + 2 * (E + base));
            srcs[0] = sv.x; srcs[1] = sv.z;
            dsts[0] = dv.x; dsts[1] = dv.z;
        }
    } else {                                   // scalar tail / odd shapes
        ne = 0;
        for (int e = base; e < E && e < base + 2; ++e, ++ne) {
            srcs[ne] = is32 ? eiw[e] : eiw[2 * e];
            dsts[ne] = is32 ? eiw[E + e] : eiw[2 * (E + e)];
        }
    }

#pragma unroll
    for (int j = 0; j < 2; ++j) {
        if (j >= ne) break;
        int dst = dsts[j];
        int pos = atomicAdd(&cnt[dst], 1);
        if (pos < CAP) {
            slots[(size_t)dst * CAP + pos] = srcs[j];
        } else {                               // essentially never
            int o = atomicAdd(ovfcnt, 1);
            ovf[2 * o]     = srcs[j];
            ovf[2 * o + 1] = dst;
        }
    }
}

// ---------------------------------------------------------------------------
// K2: fused atomic-free gather + projection. 256 threads, grid-stride over
// 32-node tiles (V staged to LDS once per block, not per tile).
// Phase A: group g (16 lanes, lane j = rank) sums U[src][j] over the node's
//          slot list, UNROLLED x4 with clamped-index predication: indices
//          are selected to a known-valid slot BEFORE the load (poison slots
//          beyond deg are never dereferenced), giving 4 independent loads in
//          flight per group instead of a serial latency chain.
// Phase B: thread (q = t&31, w = t>>5) emits 4 nodes x float4 columns of
//          (accs/deg) @ V; nontemporal stores keep the 102 MB output stream
//          from evicting L2/L3-resident U and slots.
// Overflow fallback (deg > CAP) scans the tiny global list: correct for
// arbitrary inputs, never taken on random graphs.
// ---------------------------------------------------------------------------
__global__ __launch_bounds__(256) void gather_project(
        const float* __restrict__ U,
        const float* __restrict__ V,
        const int* __restrict__ cnt,
        const int* __restrict__ slots,
        const int* __restrict__ ovfcnt,
        const int* __restrict__ ovf,
        float* __restrict__ out, int N, int ntiles) {
    __shared__ float4 Vs4[RANK * EMBED_DIM / 4];  // 8 KB
    __shared__ float accs[32][RANK];              // 2 KB
    __shared__ float sinv[32];
    __shared__ int   scnt[32];
    __shared__ int4  sslot4[32 * CAP / 4];        // 2 KB, flat/linear

    const int t = threadIdx.x;
    const float4* V4 = (const float4*)V;
    Vs4[t]       = V4[t];
    Vs4[t + 256] = V4[t + 256];

    const int g = t >> 4;   // node group 0..15 (phase A)
    const int j = t & 15;   // rank lane       (phase A)
    const int q = t & 31;   // float4 column   (phase B)
    const int w = t >> 5;   // node quad       (phase B)
    const int* sslot = (const int*)sslot4;

    for (int tile = blockIdx.x; tile < ntiles; tile += gridDim.x) {
        const int n0 = tile * 32;
        __syncthreads();               // prev tile phase-B done; Vs4 visible

        if (t < 32) {
            int n = n0 + t;
            int c = (n < N) ? cnt[n] : 0;
            scnt[t] = c;
            sinv[t] = 1.0f / fmaxf((float)c, 1.0f);
        }
        if (t < 128) {                 // 32 nodes x 16 ints = 128 int4, linear
            const int4* g4 = (const int4*)(slots + (size_t)n0 * CAP);
            if (n0 + (t >> 2) < N) sslot4[t] = g4[t];
        }
        __syncthreads();

#pragma unroll
        for (int half = 0; half < 2; ++half) {
            int nd = half * 16 + g;
            int n = n0 + nd;
            float acc = 0.f;
            if (n < N) {
                int deg = scnt[nd];
                int k = deg < CAP ? deg : CAP;
                const int* sl = sslot + nd * CAP;
                for (int e = 0; e < k; e += 4) {
                    // e < k => slot e valid. Clamp higher indices to slot e
                    // (valid) so no poison index is ever dereferenced.
                    int s0 = sl[e];
                    int s1 = (e + 1 < k) ? sl[e + 1] : s0;
                    int s2 = (e + 2 < k) ? sl[e + 2] : s0;
                    int s3 = (e + 3 < k) ? sl[e + 3] : s0;
                    float u0 = U[(size_t)s0 * RANK + j];   // 4 independent
                    float u1 = U[(size_t)s1 * RANK + j];   // loads in flight
                    float u2 = U[(size_t)s2 * RANK + j];
                    float u3 = U[(size_t)s3 * RANK + j];
                    acc += u0;
                    acc += (e + 1 < k) ? u1 : 0.f;
                    acc += (e + 2 < k) ? u2 : 0.f;
                    acc += (e + 3 < k) ? u3 : 0.f;
                }
                if (deg > CAP) {                    // correctness fallback
                    int m = *ovfcnt;
                    for (int i = 0; i < m; ++i)
                        if (ovf[2 * i + 1] == n)
                            acc += U[(size_t)ovf[2 * i] * RANK + j];
                }
            }
            accs[nd][j] = acc;
        }
        __syncthreads();

#pragma unroll
        for (int r = 0; r < 4; ++r) {
            int nd = 4 * w + r;
            float4 a4 = make_float4(0.f, 0.f, 0.f, 0.f);
#pragma unroll
            for (int k = 0; k < RANK; ++k) {
                float a = accs[nd][k];              // broadcast / 2-way: free
                float4 v = Vs4[k * 32 + q];
                a4.x = fmaf(a, v.x, a4.x);
                a4.y = fmaf(a, v.y, a4.y);
                a4.z = fmaf(a, v.z, a4.z);
                a4.w = fmaf(a, v.w, a4.w);
            }
            float s = sinv[nd];
            int n = n0 + nd;
            if (n < N) {
                floatx4 o;
                o.x = a4.x * s; o.y = a4.y * s; o.z = a4.z * s; o.w = a4.w * s;
                __builtin_nontemporal_store(
                    o, (floatx4*)out + (size_t)n * (EMBED_DIM / 4) + q);
            }
        }
    }
}

extern "C" void kernel_launch(void* const* d_in, const int* in_sizes, int n_in,
                              void* d_out, int out_size, void* d_ws, size_t ws_size,
                              hipStream_t stream) {
    const float* U = (const float*)d_in[0];
    const float* V = (const float*)d_in[1];
    const int* EI = (const int*)d_in[2];
    float* out = (float*)d_out;

    const int N = in_sizes[0] / RANK;   // 200000
    const int E = in_sizes[2] / 2;      // 640000
    const int nwords = in_sizes[2];     // >= word count under both layouts

    // workspace (int32): cnt[N] | ovfcnt[1] | pad | slots[N*CAP] | ovf[2E]
    int* wsI = (int*)d_ws;
    int* cnt = wsI;
    int* ovfcnt = wsI + N;
    const int slots_off = (N + 1 + 15) & ~15;   // 16B-align slots for int4
    int* slots = wsI + slots_off;
    int* ovf = slots + (size_t)N * CAP;         // N*CAP % 4 == 0

    // zero cnt + ovfcnt only (0.8 MB)
    (void)hipMemsetAsync(d_ws, 0, (size_t)(N + 1) * sizeof(int), stream);

    fill_slots<<<(E / 2 + 255) / 256, 256, 0, stream>>>(
        EI, cnt, ovfcnt, slots, ovf, E, nwords);

    const int ntiles = (N + 31) / 32;           // 6250
    const int nblk = ntiles < 2560 ? ntiles : 2560;
    gather_project<<<nblk, 256, 0, stream>>>(
        U, V, cnt, slots, ovfcnt, ovf, out, N, ntiles);
}

// Round 7
// 174.819 us; speedup vs baseline: 5.8553x; 1.0318x over previous
//
#include <hip/hip_runtime.h>

#define RANK 16
#define EMBED_DIM 128
#define CAP 16   // slot capacity; Poisson(3.2) P(deg>16) ~ 1e-8/node.
                 // Overflow list keeps arbitrary inputs correct.

typedef float floatx4 __attribute__((ext_vector_type(4)));  // clang-native:
// __builtin_nontemporal_store accepts this (HIP float4 is a class, rejected).

__device__ inline floatx4 shflx4(floatx4 v, int mask) {
    floatx4 r;
    r.x = __shfl_xor(v.x, mask);
    r.y = __shfl_xor(v.y, mask);
    r.z = __shfl_xor(v.z, mask);
    r.w = __shfl_xor(v.w, mask);
    return r;
}

// ---------------------------------------------------------------------------
// K1: one pass over edges, 2 edges/thread (16B vector loads, 1250 blocks ->
// ~5 blocks/CU TLP to hide atomic+scattered-store latency). Per-block dtype
// detect (odd 32-bit words of int64 layout are high halves of node ids <
// 2^31 -> all zero; int32 layout -> random ids, surely nonzero among 256
// samples). Then:
//   pos = atomicAdd(cnt[dst]); pos < CAP ? slots[dst*CAP+pos] = src
//                                        : append (src,dst) to overflow list.
// ---------------------------------------------------------------------------
__global__ __launch_bounds__(256) void fill_slots(
        const int* __restrict__ eiw,   // edge_index as 32-bit words
        int* __restrict__ cnt,         // [N], pre-zeroed
        int* __restrict__ ovfcnt,      // [1], pre-zeroed
        int* __restrict__ slots,       // [N*CAP]
        int* __restrict__ ovf,         // [2*E]
        int E, int nwords) {
    __shared__ int iflag;
    if (threadIdx.x == 0) iflag = 0;
    __syncthreads();
    {
        int w = 2 * threadIdx.x + 1;
        unsigned int v = (w < nwords) ? ((const unsigned int*)eiw)[w] : 0u;
        if (v) atomicOr(&iflag, 1);            // LDS atomic
    }
    __syncthreads();
    const bool is32 = (iflag != 0);

    const int base = (blockIdx.x * 256 + threadIdx.x) * 2;
    if (base >= E) return;

    int srcs[2], dsts[2];
    int ne;
    if ((E & 1) == 0 && base + 1 < E) {        // vector path (aligned: E even)
        ne = 2;
        if (is32) {                            // int32 layout: int2 loads
            int2 s = *(const int2*)(eiw + base);
            int2 d = *(const int2*)(eiw + E + base);
            srcs[0] = s.x; srcs[1] = s.y;
            dsts[0] = d.x; dsts[1] = d.y;
        } else {                               // int64 layout: int4, low words
            int4 sv = *(const int4*)(eiw + 2 * base);
            int4 dv = *(const int4*)(eiw + 2 * (E + base));
            srcs[0] = sv.x; srcs[1] = sv.z;
            dsts[0] = dv.x; dsts[1] = dv.z;
        }
    } else {                                   // scalar tail / odd shapes
        ne = 0;
        for (int e = base; e < E && e < base + 2; ++e, ++ne) {
            srcs[ne] = is32 ? eiw[e] : eiw[2 * e];
            dsts[ne] = is32 ? eiw[E + e] : eiw[2 * (E + e)];
        }
    }

#pragma unroll
    for (int j = 0; j < 2; ++j) {
        if (j >= ne) break;
        int dst = dsts[j];
        int pos = atomicAdd(&cnt[dst], 1);
        if (pos < CAP) {
            slots[(size_t)dst * CAP + pos] = srcs[j];
        } else {                               // essentially never
            int o = atomicAdd(ovfcnt, 1);
            ovf[2 * o]     = srcs[j];
            ovf[2 * o + 1] = dst;
        }
    }
}

// ---------------------------------------------------------------------------
// K2: fused atomic-free gather + projection. 256 threads, 64 nodes per block
// (grid = ceil(N/64), one V/slot staging per block).
// Phase A: group g (16 lanes) owns node nd. Lane l covers edge-slot (l>>2)
//          and rank-quad (l&3): ONE global_load_dwordx4 per 4 edges per
//          group (vs 4 dword loads before), 8-edge unroll -> 2 loads in
//          flight. Per-lane float4 partials combined once at the end via 2
//          shfl_xor rounds (masks 4,8 — intra-group). Deterministic.
// Phase B: thread (q = t&31, w = t>>5) emits 8 nodes x float4 column of
//          (accs/deg) @ V with V LDS-cached; nontemporal stores keep the
//          102 MB output stream from evicting L2/L3-resident U and slots.
// Overflow fallback (deg > CAP) scans the tiny global list: correct for
// arbitrary inputs, never taken on random graphs.
// ---------------------------------------------------------------------------
__global__ __launch_bounds__(256) void gather_project(
        const float* __restrict__ U,
        const float* __restrict__ V,
        const int* __restrict__ cnt,
        const int* __restrict__ slots,
        const int* __restrict__ ovfcnt,
        const int* __restrict__ ovf,
        float* __restrict__ out, int N) {
    __shared__ float4  Vs4[RANK * EMBED_DIM / 4];  // 8 KB
    __shared__ floatx4 accs4[64][4];               // 4 KB
    __shared__ float   sinv[64];
    __shared__ int     scnt[64];
    __shared__ int4    sslot4[64 * CAP / 4];       // 4 KB, flat/linear

    const int t = threadIdx.x;
    const float4* V4 = (const float4*)V;
    Vs4[t]       = V4[t];
    Vs4[t + 256] = V4[t + 256];

    const int n0 = blockIdx.x * 64;

    if (t < 64) {
        int n = n0 + t;
        int c = (n < N) ? cnt[n] : 0;
        scnt[t] = c;
        sinv[t] = 1.0f / fmaxf((float)c, 1.0f);
    }
    {   // 64 nodes x 16 ints = 256 int4, linear ds_write_b128
        const int4* g4 = (const int4*)(slots + (size_t)n0 * CAP);
        if (n0 + (t >> 2) < N) sslot4[t] = g4[t];
    }
    __syncthreads();

    const int* sslot = (const int*)sslot4;
    const int g    = t >> 4;   // node group 0..15
    const int l    = t & 15;   // lane in group
    const int es   = l >> 2;   // edge slot 0..3
    const int quad = l & 3;    // rank quad 0..3

#pragma unroll
    for (int half = 0; half < 4; ++half) {
        int nd = half * 16 + g;
        int n = n0 + nd;
        int deg = scnt[nd];
        int k = deg < CAP ? deg : CAP;
        const int* sl = sslot + nd * CAP;
        floatx4 a = (floatx4)0.f;
        for (int e = 0; e < k; e += 8) {
            // e < k inside loop => k >= 1 => clamped index valid; poison
            // slots beyond deg are never dereferenced.
            int e0 = e + es;
            int e1 = e + 4 + es;
            int i0 = e0 < k ? e0 : k - 1;
            int i1 = e1 < k ? e1 : k - 1;
            int s0 = sl[i0];
            int s1 = sl[i1];
            floatx4 u0 = *(const floatx4*)(U + (size_t)s0 * RANK + 4 * quad);
            floatx4 u1 = *(const floatx4*)(U + (size_t)s1 * RANK + 4 * quad);
            if (e0 < k) a += u0;
            if (e1 < k) a += u1;
        }
        // combine the 4 edge-slot partials (masks stay inside the 16-lane group)
        a += shflx4(a, 4);
        a += shflx4(a, 8);
        if (l < 4) {                            // lane l holds rank-quad l
            if (deg > CAP) {                    // correctness fallback
                int m = *ovfcnt;
                for (int i = 0; i < m; ++i)
                    if (ovf[2 * i + 1] == n)
                        a += *(const floatx4*)(U + (size_t)ovf[2 * i] * RANK + 4 * l);
            }
            accs4[nd][l] = a;
        }
    }
    __syncthreads();

    const float* accsf = (const float*)accs4;
    const int q = t & 31;   // float4 column
    const int w = t >> 5;   // node octet
#pragma unroll
    for (int r = 0; r < 8; ++r) {
        int nd = w * 8 + r;
        floatx4 o = (floatx4)0.f;
#pragma unroll
        for (int k = 0; k < RANK; ++k) {
            float a = accsf[nd * 16 + k];       // 2-way broadcast: free
            float4 v = Vs4[k * 32 + q];
            o.x = fmaf(a, v.x, o.x);
            o.y = fmaf(a, v.y, o.y);
            o.z = fmaf(a, v.z, o.z);
            o.w = fmaf(a, v.w, o.w);
        }
        int n = n0 + nd;
        if (n < N) {
            o *= sinv[nd];
            __builtin_nontemporal_store(
                o, (floatx4*)out + (size_t)n * (EMBED_DIM / 4) + q);
        }
    }
}

extern "C" void kernel_launch(void* const* d_in, const int* in_sizes, int n_in,
                              void* d_out, int out_size, void* d_ws, size_t ws_size,
                              hipStream_t stream) {
    const float* U = (const float*)d_in[0];
    const float* V = (const float*)d_in[1];
    const int* EI = (const int*)d_in[2];
    float* out = (float*)d_out;

    const int N = in_sizes[0] / RANK;   // 200000
    const int E = in_sizes[2] / 2;      // 640000
    const int nwords = in_sizes[2];     // >= word count under both layouts

    // workspace (int32): cnt[N] | ovfcnt[1] | pad | slots[N*CAP] | ovf[2E]
    int* wsI = (int*)d_ws;
    int* cnt = wsI;
    int* ovfcnt = wsI + N;
    const int slots_off = (N + 1 + 15) & ~15;   // 16B-align slots for int4
    int* slots = wsI + slots_off;
    int* ovf = slots + (size_t)N * CAP;

    // zero cnt + ovfcnt only (0.8 MB)
    (void)hipMemsetAsync(d_ws, 0, (size_t)(N + 1) * sizeof(int), stream);

    fill_slots<<<(E / 2 + 255) / 256, 256, 0, stream>>>(
        EI, cnt, ovfcnt, slots, ovf, E, nwords);

    gather_project<<<(N + 63) / 64, 256, 0, stream>>>(
        U, V, cnt, slots, ovfcnt, ovf, out, N);
}